// Round 8
// baseline (141.548 us; speedup 1.0000x reference)
//
#include <hip/hip_runtime.h>

typedef _Float16 f16;
typedef __attribute__((ext_vector_type(8))) f16 f16x8;
typedef __attribute__((ext_vector_type(4))) f16 f16x4;
typedef __attribute__((ext_vector_type(2))) __fp16 h16x2;   // cvt_pkrtz result type
typedef __attribute__((ext_vector_type(4))) float floatx4;

#define NPIX 4096
#define KT   128          // keys per attention tile
#define VROW 136          // padded LDS row (128 keys + 8) in f16
#define NSPLIT 4          // split-K factor in attention

// ---------------------------------------------------------------------------
// Kernel 0: convert w_qkv (384x128) and w_proj (128x128) fp32 -> f16 once.
// Q rows (o<128) of w_qkv pre-scaled by SCALE*log2(e).
// ---------------------------------------------------------------------------
__global__ __launch_bounds__(256) void cvt_w(
    const float* __restrict__ wq, const float* __restrict__ wp,
    f16* __restrict__ wh, f16* __restrict__ wph)
{
    const int idx = (blockIdx.x * 256 + threadIdx.x) * 4;   // < 65536
    const float qs = 0.17677669529663687f * 1.4426950408889634f;
    float4 v;
    f16* dst;
    if (idx < 49152) { v = *(const float4*)(wq + idx); dst = wh + idx; }
    else             { v = *(const float4*)(wp + (idx - 49152)); dst = wph + (idx - 49152); }
    if (idx < 16384) { v.x *= qs; v.y *= qs; v.z *= qs; v.w *= qs; }  // Q rows
    h16x2 a = __builtin_amdgcn_cvt_pkrtz(v.x, v.y);
    h16x2 b = __builtin_amdgcn_cvt_pkrtz(v.z, v.w);
    f16x4 h; h[0] = (f16)a[0]; h[1] = (f16)a[1]; h[2] = (f16)b[0]; h[3] = (f16)b[1];
    *(f16x4*)dst = h;
}

// ---------------------------------------------------------------------------
// Kernel 1: QKV projection, LDS-free MFMA GEMM, o-tile split across blocks.
// grid (64 p-tiles, 6 y, 4 b) = 1536 blocks. X gather serves both A-role
// (Q/K: C[p][o]) and B-role (V: C[o][p]). W frags straight from f16 global.
// ---------------------------------------------------------------------------
__global__ __launch_bounds__(256) void qkv_mfma(
    const float* __restrict__ x, const f16* __restrict__ wh,
    f16* __restrict__ qh, f16* __restrict__ kh, f16* __restrict__ vth)
{
    const int tid  = threadIdx.x;
    const int wave = tid >> 6;
    const int lane = tid & 63;
    const int quad = lane >> 4;
    const int l16  = lane & 15;
    const int pbase = blockIdx.x * 64;
    const int y     = blockIdx.y;      // 0-1=q, 2-3=k, 4-5=v
    const int b     = blockIdx.z;
    const int p_col = pbase + wave * 16 + l16;

    const float* xb = x + (size_t)b * 128 * NPIX;

    f16x8 xf[4];
#pragma unroll
    for (int kc = 0; kc < 4; ++kc) {
        const int c0 = kc * 32 + quad * 8;
        float e[8];
#pragma unroll
        for (int j = 0; j < 8; ++j)
            e[j] = xb[(size_t)(c0 + j) * NPIX + p_col];
#pragma unroll
        for (int j = 0; j < 4; ++j) {
            h16x2 pk = __builtin_amdgcn_cvt_pkrtz(e[2 * j], e[2 * j + 1]);
            xf[kc][2 * j] = (f16)pk[0]; xf[kc][2 * j + 1] = (f16)pk[1];
        }
    }

    floatx4 acc[4];
#pragma unroll
    for (int i = 0; i < 4; ++i) acc[i] = floatx4{0.f, 0.f, 0.f, 0.f};

    if (y < 4) {
        // C[p][o]: A = X^T (regs), B = W (global f16)
#pragma unroll
        for (int n = 0; n < 4; ++n)
#pragma unroll
            for (int kc = 0; kc < 4; ++kc) {
                f16x8 wf = *(const f16x8*)&wh[(size_t)(y * 64 + n * 16 + l16) * 128 + kc * 32 + quad * 8];
                acc[n] = __builtin_amdgcn_mfma_f32_16x16x32_f16(xf[kc], wf, acc[n], 0, 0, 0);
            }
        f16* dst = (y < 2) ? qh : kh;
#pragma unroll
        for (int n = 0; n < 4; ++n) {
            const int og    = y * 64 + n * 16 + l16;
            const int local = og & 127;
            const int head  = local >> 5;
            const int d     = local & 31;
            f16* base = dst + (size_t)(b * 4 + head) * NPIX * 32;
#pragma unroll
            for (int r = 0; r < 4; ++r) {
                const int p = pbase + wave * 16 + quad * 4 + r;
                base[(size_t)p * 32 + d] = (f16)acc[n][r];
            }
        }
    } else {
        // C[o][p]: A = W (global f16), B = X (regs)
#pragma unroll
        for (int m = 0; m < 4; ++m)
#pragma unroll
            for (int kc = 0; kc < 4; ++kc) {
                f16x8 wf = *(const f16x8*)&wh[(size_t)(y * 64 + m * 16 + l16) * 128 + kc * 32 + quad * 8];
                acc[m] = __builtin_amdgcn_mfma_f32_16x16x32_f16(wf, xf[kc], acc[m], 0, 0, 0);
            }
#pragma unroll
        for (int m = 0; m < 4; ++m)
#pragma unroll
            for (int r = 0; r < 4; ++r) {
                const int ov   = (y - 4) * 64 + m * 16 + quad * 4 + r;
                const int head = ov >> 5;
                const int d    = ov & 31;
                vth[((size_t)(b * 4 + head) * 32 + d) * NPIX + p_col] = (f16)acc[m][r];
            }
    }
}

// ---------------------------------------------------------------------------
// Kernel 2: flash attention via S^T = K*Q^T, split-K 4-way, 32 q/wave.
// grid 2048 = 8 blocks/CU (bh in low bits -> XCD-local K/V, L2-resident).
// Row sums computed by MFMA ones-trick: B-frag has 1.0 only where l16==0,
// so D[q][0] accumulates sum_k P[q][k] -- removes all in-loop VALU adds.
// PV uses K=32 MFMAs via in-lane concat of two 16-key C-layout tiles.
// Partials: O (unnormalized, f16) -> po[split][bh][q][32]; l -> pl fp32.
// ---------------------------------------------------------------------------
__global__ __launch_bounds__(256, 4) void attn_kernel(
    const f16* __restrict__ qh, const f16* __restrict__ kh,
    const f16* __restrict__ vth, f16* __restrict__ po, float* __restrict__ pl)
{
    __shared__ f16 klds[KT * 32];      // [key][d] 8 KB
    __shared__ f16 vlds[32 * VROW];    // [d][key] padded 8.5 KB

    const int tid  = threadIdx.x;
    const int wave = tid >> 6;
    const int lane = tid & 63;
    const int quad = lane >> 4;
    const int l16  = lane & 15;

    const int n     = blockIdx.x;              // 0..2047
    const int bh    = (n & 7) * 2 + ((n >> 3) & 1);
    const int qblk  = (n >> 4) & 31;           // 0..31 (128 q each)
    const int split = (n >> 9) & 3;            // 0..3 (1024 keys each)
    const int qbase = qblk * 128 + wave * 32;

    const f16* kb = kh + (size_t)bh * NPIX * 32;
    const f16* vb = vth + (size_t)bh * 32 * NPIX;

    // Q B-frags (B[k=d][n=q]) for two 16-q subtiles
    f16x8 qB[2];
#pragma unroll
    for (int h = 0; h < 2; ++h)
        qB[h] = *(const f16x8*)(qh + ((size_t)bh * NPIX + qbase + h * 16 + l16) * 32 + quad * 8);

    // ones B-frag: B[k][n] = (n==0) -> D[q][0] = row sum
    f16x8 ones;
#pragma unroll
    for (int j = 0; j < 8; ++j) ones[j] = (l16 == 0) ? (f16)1.0f : (f16)0.0f;

    floatx4 oacc[2][2], lacc[2];
#pragma unroll
    for (int h = 0; h < 2; ++h) {
        lacc[h] = floatx4{0.f, 0.f, 0.f, 0.f};
#pragma unroll
        for (int dh = 0; dh < 2; ++dh) oacc[h][dh] = floatx4{0.f, 0.f, 0.f, 0.f};
    }

    for (int kt = split * 8; kt < split * 8 + 8; ++kt) {
        __syncthreads();
        {   // stage K tile: 128 keys x 32 d = 8 KB contiguous
            const int4* src = (const int4*)(kb + (size_t)kt * KT * 32);
            ((int4*)klds)[tid]       = src[tid];
            ((int4*)klds)[tid + 256] = src[tid + 256];
        }
        {   // stage V tile: 32 d-rows x 128 keys into padded rows
            const int r  = tid >> 3;
            const int cc = (tid & 7) * 2;
            const int4* vsrc = (const int4*)(vb + (size_t)r * NPIX + kt * KT + cc * 8);
            int4 v0 = vsrc[0], v1 = vsrc[1];
            int4* vdst = (int4*)(vlds + r * VROW + cc * 8);
            vdst[0] = v0; vdst[1] = v1;
        }
        __syncthreads();

        // K A-frags shared across both h subtiles
        f16x8 kf[8];
#pragma unroll
        for (int t = 0; t < 8; ++t)
            kf[t] = *(const f16x8*)&klds[(t * 16 + l16) * 32 + quad * 8];

#pragma unroll
        for (int h = 0; h < 2; ++h) {
            floatx4 st[8];
            const floatx4 z0 = {0.f, 0.f, 0.f, 0.f};
#pragma unroll
            for (int t = 0; t < 8; ++t)
                st[t] = __builtin_amdgcn_mfma_f32_16x16x32_f16(kf[t], qB[h], z0, 0, 0, 0);

            f16x4 paf[8];
#pragma unroll
            for (int t = 0; t < 8; ++t) {
                float e0 = __builtin_amdgcn_exp2f(st[t][0]);
                float e1 = __builtin_amdgcn_exp2f(st[t][1]);
                float e2 = __builtin_amdgcn_exp2f(st[t][2]);
                float e3 = __builtin_amdgcn_exp2f(st[t][3]);
                h16x2 lo = __builtin_amdgcn_cvt_pkrtz(e0, e1);
                h16x2 hi = __builtin_amdgcn_cvt_pkrtz(e2, e3);
                paf[t][0] = (f16)lo[0]; paf[t][1] = (f16)lo[1];
                paf[t][2] = (f16)hi[0]; paf[t][3] = (f16)hi[1];
            }
            // PV + row-sum: K=32 over concat key-groups (tiles 2g, 2g+1)
#pragma unroll
            for (int g = 0; g < 4; ++g) {
                f16x8 pA;
#pragma unroll
                for (int j = 0; j < 4; ++j) { pA[j] = paf[2 * g][j]; pA[4 + j] = paf[2 * g + 1][j]; }
                lacc[h] = __builtin_amdgcn_mfma_f32_16x16x32_f16(pA, ones, lacc[h], 0, 0, 0);
#pragma unroll
                for (int dh = 0; dh < 2; ++dh) {
                    const f16* vrow = &vlds[(dh * 16 + l16) * VROW + 32 * g + quad * 4];
                    f16x4 v0 = *(const f16x4*)(vrow);
                    f16x4 v1 = *(const f16x4*)(vrow + 16);
                    f16x8 vB;
#pragma unroll
                    for (int j = 0; j < 4; ++j) { vB[j] = v0[j]; vB[4 + j] = v1[j]; }
                    oacc[h][dh] = __builtin_amdgcn_mfma_f32_16x16x32_f16(pA, vB, oacc[h][dh], 0, 0, 0);
                }
            }
        }
    }

    // epilogue: store unnormalized partials.
    // lacc C-layout: sum(q=quad*4+r) lives at lane {l16==0, quad}, reg r.
    const size_t bq = (size_t)(split * 16 + bh) * NPIX;
#pragma unroll
    for (int h = 0; h < 2; ++h) {
        if (l16 == 0) {
#pragma unroll
            for (int r = 0; r < 4; ++r)
                pl[bq + qbase + h * 16 + quad * 4 + r] = lacc[h][r];
        }
        f16* poh = po + (bq + qbase + h * 16) * 32;
#pragma unroll
        for (int r = 0; r < 4; ++r) {
            poh[(quad * 4 + r) * 32 + l16]      = (f16)oacc[h][0][r];
            poh[(quad * 4 + r) * 32 + 16 + l16] = (f16)oacc[h][1][r];
        }
    }
}

// ---------------------------------------------------------------------------
// Kernel 3: output projection with inline split-K combine.
// bf[kc] (head kc's att row for pixel p_col) = (sum_s po[s]) / (sum_s pl[s]),
// built in registers; then C[o][p] = Wp x att^T + bias. grid (64,2,4)=512.
// ---------------------------------------------------------------------------
__global__ __launch_bounds__(256) void proj_mfma(
    const f16* __restrict__ po, const float* __restrict__ pl,
    const f16* __restrict__ wph, const float* __restrict__ bp,
    float* __restrict__ out)
{
    const int tid  = threadIdx.x;
    const int wave = tid >> 6;
    const int lane = tid & 63;
    const int quad = lane >> 4;
    const int l16  = lane & 15;
    const int pbase = blockIdx.x * 64;
    const int obase = blockIdx.y * 64;
    const int b     = blockIdx.z;
    const int p_col = pbase + wave * 16 + l16;

    f16x8 bf[4];
#pragma unroll
    for (int kc = 0; kc < 4; ++kc) {
        const int bh = b * 4 + kc;
        float sums[8] = {0.f, 0.f, 0.f, 0.f, 0.f, 0.f, 0.f, 0.f};
        float lt = 0.f;
#pragma unroll
        for (int s = 0; s < NSPLIT; ++s) {
            const size_t bq = (size_t)(s * 16 + bh) * NPIX + p_col;
            f16x8 a = *(const f16x8*)(po + bq * 32 + quad * 8);
#pragma unroll
            for (int j = 0; j < 8; ++j) sums[j] += (float)a[j];
            lt += pl[bq];
        }
        const float inv = 1.0f / lt;
#pragma unroll
        for (int j = 0; j < 4; ++j) {
            h16x2 pk = __builtin_amdgcn_cvt_pkrtz(sums[2 * j] * inv, sums[2 * j + 1] * inv);
            bf[kc][2 * j] = (f16)pk[0]; bf[kc][2 * j + 1] = (f16)pk[1];
        }
    }

    floatx4 acc[4];
#pragma unroll
    for (int m = 0; m < 4; ++m) acc[m] = floatx4{0.f, 0.f, 0.f, 0.f};
#pragma unroll
    for (int m = 0; m < 4; ++m)
#pragma unroll
        for (int kc = 0; kc < 4; ++kc) {
            f16x8 af = *(const f16x8*)&wph[(size_t)(obase + m * 16 + l16) * 128 + kc * 32 + quad * 8];
            acc[m] = __builtin_amdgcn_mfma_f32_16x16x32_f16(af, bf[kc], acc[m], 0, 0, 0);
        }

#pragma unroll
    for (int m = 0; m < 4; ++m)
#pragma unroll
        for (int r = 0; r < 4; ++r) {
            const int o = obase + m * 16 + quad * 4 + r;
            out[((size_t)b * 128 + o) * NPIX + p_col] = acc[m][r] + bp[o];
        }
}

// ---------------------------------------------------------------------------
extern "C" void kernel_launch(void* const* d_in, const int* in_sizes, int n_in,
                              void* d_out, int out_size, void* d_ws, size_t ws_size,
                              hipStream_t stream)
{
    const float* x      = (const float*)d_in[0];
    const float* w_qkv  = (const float*)d_in[1];
    const float* w_proj = (const float*)d_in[2];
    const float* b_proj = (const float*)d_in[3];
    float* out = (float*)d_out;

    char* ws = (char*)d_ws;
    f16*   qh  = (f16*)(ws);                              // 4 MB [bh][p][32], pre-scaled
    f16*   kh  = (f16*)(ws + (4u << 20));                 // 4 MB [bh][p][32]
    f16*   vth = (f16*)(ws + (8u << 20));                 // 4 MB [bh][d][p]
    f16*   wh  = (f16*)(ws + (12u << 20));                // 96 KB
    f16*   wph = (f16*)(ws + (12u << 20) + (96u << 10));  // 32 KB
    float* pl  = (float*)(ws + (12u << 20) + (128u << 10)); // 1 MB [4][16][4096] f32
    f16*   po  = (f16*)(ws + (13u << 20) + (128u << 10)); // 16.8 MB [4][16][4096][32] f16

    cvt_w<<<dim3(64, 1, 1), 256, 0, stream>>>(w_qkv, w_proj, wh, wph);
    qkv_mfma<<<dim3(64, 6, 4), 256, 0, stream>>>(x, wh, qh, kh, vth);
    attn_kernel<<<dim3(2048, 1, 1), 256, 0, stream>>>(qh, kh, vth, po, pl);
    proj_mfma<<<dim3(64, 2, 4), 256, 0, stream>>>(po, pl, wph, b_proj, out);
}

// Round 9
// 132.016 us; speedup vs baseline: 1.0722x; 1.0722x over previous
//
#include <hip/hip_runtime.h>

typedef _Float16 f16;
typedef __attribute__((ext_vector_type(8))) f16 f16x8;
typedef __attribute__((ext_vector_type(4))) f16 f16x4;
typedef __attribute__((ext_vector_type(2))) __fp16 h16x2;   // cvt_pkrtz result type
typedef __attribute__((ext_vector_type(4))) float floatx4;

#define NPIX 4096
#define KT   128          // keys per attention tile
#define VROW 136          // padded LDS row (128 keys + 8) in f16
#define XROW 66           // padded fp32 x-tile row (64 pixels + 2)
#define NSPLIT 4          // split-K factor in attention

// ---------------------------------------------------------------------------
// Kernel 1: QKV projection MFMA GEMM with LDS staging (no cvt prepass).
// grid (64 p-tiles, 6 y, 4 b) = 1536 blocks, 50 KB LDS -> 3 blocks/CU.
// x-tile staged fp32 [128c][66p] (pad 66: quad c-step 8 rows = 528 words
// = 16 mod 32 banks -> 2-way access = free); W staged f16 [64o][136c].
// Q rows (y<2) pre-scaled by SCALE*log2(e) during W staging.
// ---------------------------------------------------------------------------
__global__ __launch_bounds__(256) void qkv_mfma(
    const float* __restrict__ x, const float* __restrict__ wq,
    f16* __restrict__ qh, f16* __restrict__ kh, f16* __restrict__ vth)
{
    __shared__ float xlds[128 * XROW];   // 33.8 KB
    __shared__ f16   wlds[64 * 136];     // 17.4 KB

    const int tid  = threadIdx.x;
    const int wave = tid >> 6;
    const int lane = tid & 63;
    const int quad = lane >> 4;
    const int l16  = lane & 15;
    const int pbase = blockIdx.x * 64;
    const int y     = blockIdx.y;      // 0-1=q, 2-3=k, 4-5=v
    const int b     = blockIdx.z;
    const int p_col = pbase + wave * 16 + l16;

    const float* xb = x + (size_t)b * 128 * NPIX;
    const float qs = (y < 2) ? 0.17677669529663687f * 1.4426950408889634f : 1.0f;

    // stage W tile [64o][128c] fp32 -> f16 (2048 float4)
#pragma unroll
    for (int i = 0; i < 8; ++i) {
        const int idx = i * 256 + tid;
        const int o = idx >> 5, ch = idx & 31;
        float4 wv = *(const float4*)(wq + (size_t)(y * 64 + o) * 128 + ch * 4);
        h16x2 a = __builtin_amdgcn_cvt_pkrtz(wv.x * qs, wv.y * qs);
        h16x2 c = __builtin_amdgcn_cvt_pkrtz(wv.z * qs, wv.w * qs);
        f16x4 h; h[0] = (f16)a[0]; h[1] = (f16)a[1]; h[2] = (f16)c[0]; h[3] = (f16)c[1];
        *(f16x4*)&wlds[o * 136 + ch * 4] = h;
    }
    // stage x tile [128c][64p] fp32, coalesced float4 along p (2048 float4)
#pragma unroll
    for (int i = 0; i < 8; ++i) {
        const int idx = i * 256 + tid;
        const int c = idx >> 4, p4 = (idx & 15) * 4;
        float4 xv = *(const float4*)(xb + (size_t)c * NPIX + pbase + p4);
        *(float4*)&xlds[c * XROW + p4] = xv;
    }
    __syncthreads();

    // X fragments (serve both A-role for Q/K and B-role for V)
    f16x8 xf[4];
#pragma unroll
    for (int kc = 0; kc < 4; ++kc) {
        const int c0 = kc * 32 + quad * 8;
        const int pl = wave * 16 + l16;
        float e[8];
#pragma unroll
        for (int j = 0; j < 8; ++j)
            e[j] = xlds[(c0 + j) * XROW + pl];
#pragma unroll
        for (int j = 0; j < 4; ++j) {
            h16x2 pk = __builtin_amdgcn_cvt_pkrtz(e[2 * j], e[2 * j + 1]);
            xf[kc][2 * j] = (f16)pk[0]; xf[kc][2 * j + 1] = (f16)pk[1];
        }
    }

    floatx4 acc[4];
#pragma unroll
    for (int i = 0; i < 4; ++i) acc[i] = floatx4{0.f, 0.f, 0.f, 0.f};

    if (y < 4) {
        // C[p][o]: A = X^T (regs), B = W (LDS)
#pragma unroll
        for (int n = 0; n < 4; ++n)
#pragma unroll
            for (int kc = 0; kc < 4; ++kc) {
                f16x8 wf = *(const f16x8*)&wlds[(n * 16 + l16) * 136 + kc * 32 + quad * 8];
                acc[n] = __builtin_amdgcn_mfma_f32_16x16x32_f16(xf[kc], wf, acc[n], 0, 0, 0);
            }
        f16* dst = (y < 2) ? qh : kh;
#pragma unroll
        for (int n = 0; n < 4; ++n) {
            const int og    = y * 64 + n * 16 + l16;
            const int local = og & 127;
            const int head  = local >> 5;
            const int d     = local & 31;
            f16* base = dst + (size_t)(b * 4 + head) * NPIX * 32;
#pragma unroll
            for (int r = 0; r < 4; ++r) {
                const int p = pbase + wave * 16 + quad * 4 + r;
                base[(size_t)p * 32 + d] = (f16)acc[n][r];
            }
        }
    } else {
        // C[o][p]: A = W (LDS), B = X (regs)
#pragma unroll
        for (int m = 0; m < 4; ++m)
#pragma unroll
            for (int kc = 0; kc < 4; ++kc) {
                f16x8 wf = *(const f16x8*)&wlds[(m * 16 + l16) * 136 + kc * 32 + quad * 8];
                acc[m] = __builtin_amdgcn_mfma_f32_16x16x32_f16(wf, xf[kc], acc[m], 0, 0, 0);
            }
#pragma unroll
        for (int m = 0; m < 4; ++m)
#pragma unroll
            for (int r = 0; r < 4; ++r) {
                const int ov   = (y - 4) * 64 + m * 16 + quad * 4 + r;
                const int head = ov >> 5;
                const int d    = ov & 31;
                vth[((size_t)(b * 4 + head) * 32 + d) * NPIX + p_col] = (f16)acc[m][r];
            }
    }
}

// ---------------------------------------------------------------------------
// Kernel 2: flash attention via S^T = K*Q^T, split-K 4-way, 32 q/wave.
// (unchanged from R8: 51.9 us, MfmaUtil 34.7%, occupancy 45%)
// ---------------------------------------------------------------------------
__global__ __launch_bounds__(256, 4) void attn_kernel(
    const f16* __restrict__ qh, const f16* __restrict__ kh,
    const f16* __restrict__ vth, f16* __restrict__ po, float* __restrict__ pl)
{
    __shared__ f16 klds[KT * 32];      // [key][d] 8 KB
    __shared__ f16 vlds[32 * VROW];    // [d][key] padded 8.5 KB

    const int tid  = threadIdx.x;
    const int wave = tid >> 6;
    const int lane = tid & 63;
    const int quad = lane >> 4;
    const int l16  = lane & 15;

    const int n     = blockIdx.x;              // 0..2047
    const int bh    = (n & 7) * 2 + ((n >> 3) & 1);
    const int qblk  = (n >> 4) & 31;           // 0..31 (128 q each)
    const int split = (n >> 9) & 3;            // 0..3 (1024 keys each)
    const int qbase = qblk * 128 + wave * 32;

    const f16* kb = kh + (size_t)bh * NPIX * 32;
    const f16* vb = vth + (size_t)bh * 32 * NPIX;

    f16x8 qB[2];
#pragma unroll
    for (int h = 0; h < 2; ++h)
        qB[h] = *(const f16x8*)(qh + ((size_t)bh * NPIX + qbase + h * 16 + l16) * 32 + quad * 8);

    f16x8 ones;
#pragma unroll
    for (int j = 0; j < 8; ++j) ones[j] = (l16 == 0) ? (f16)1.0f : (f16)0.0f;

    floatx4 oacc[2][2], lacc[2];
#pragma unroll
    for (int h = 0; h < 2; ++h) {
        lacc[h] = floatx4{0.f, 0.f, 0.f, 0.f};
#pragma unroll
        for (int dh = 0; dh < 2; ++dh) oacc[h][dh] = floatx4{0.f, 0.f, 0.f, 0.f};
    }

    for (int kt = split * 8; kt < split * 8 + 8; ++kt) {
        __syncthreads();
        {
            const int4* src = (const int4*)(kb + (size_t)kt * KT * 32);
            ((int4*)klds)[tid]       = src[tid];
            ((int4*)klds)[tid + 256] = src[tid + 256];
        }
        {
            const int r  = tid >> 3;
            const int cc = (tid & 7) * 2;
            const int4* vsrc = (const int4*)(vb + (size_t)r * NPIX + kt * KT + cc * 8);
            int4 v0 = vsrc[0], v1 = vsrc[1];
            int4* vdst = (int4*)(vlds + r * VROW + cc * 8);
            vdst[0] = v0; vdst[1] = v1;
        }
        __syncthreads();

        f16x8 kf[8];
#pragma unroll
        for (int t = 0; t < 8; ++t)
            kf[t] = *(const f16x8*)&klds[(t * 16 + l16) * 32 + quad * 8];

#pragma unroll
        for (int h = 0; h < 2; ++h) {
            floatx4 st[8];
            const floatx4 z0 = {0.f, 0.f, 0.f, 0.f};
#pragma unroll
            for (int t = 0; t < 8; ++t)
                st[t] = __builtin_amdgcn_mfma_f32_16x16x32_f16(kf[t], qB[h], z0, 0, 0, 0);

            f16x4 paf[8];
#pragma unroll
            for (int t = 0; t < 8; ++t) {
                float e0 = __builtin_amdgcn_exp2f(st[t][0]);
                float e1 = __builtin_amdgcn_exp2f(st[t][1]);
                float e2 = __builtin_amdgcn_exp2f(st[t][2]);
                float e3 = __builtin_amdgcn_exp2f(st[t][3]);
                h16x2 lo = __builtin_amdgcn_cvt_pkrtz(e0, e1);
                h16x2 hi = __builtin_amdgcn_cvt_pkrtz(e2, e3);
                paf[t][0] = (f16)lo[0]; paf[t][1] = (f16)lo[1];
                paf[t][2] = (f16)hi[0]; paf[t][3] = (f16)hi[1];
            }
#pragma unroll
            for (int g = 0; g < 4; ++g) {
                f16x8 pA;
#pragma unroll
                for (int j = 0; j < 4; ++j) { pA[j] = paf[2 * g][j]; pA[4 + j] = paf[2 * g + 1][j]; }
                lacc[h] = __builtin_amdgcn_mfma_f32_16x16x32_f16(pA, ones, lacc[h], 0, 0, 0);
#pragma unroll
                for (int dh = 0; dh < 2; ++dh) {
                    const f16* vrow = &vlds[(dh * 16 + l16) * VROW + 32 * g + quad * 4];
                    f16x4 v0 = *(const f16x4*)(vrow);
                    f16x4 v1 = *(const f16x4*)(vrow + 16);
                    f16x8 vB;
#pragma unroll
                    for (int j = 0; j < 4; ++j) { vB[j] = v0[j]; vB[4 + j] = v1[j]; }
                    oacc[h][dh] = __builtin_amdgcn_mfma_f32_16x16x32_f16(pA, vB, oacc[h][dh], 0, 0, 0);
                }
            }
        }
    }

    const size_t bq = (size_t)(split * 16 + bh) * NPIX;
#pragma unroll
    for (int h = 0; h < 2; ++h) {
        if (l16 == 0) {
#pragma unroll
            for (int r = 0; r < 4; ++r)
                pl[bq + qbase + h * 16 + quad * 4 + r] = lacc[h][r];
        }
        f16* poh = po + (bq + qbase + h * 16) * 32;
#pragma unroll
        for (int r = 0; r < 4; ++r) {
            poh[(quad * 4 + r) * 32 + l16]      = (f16)oacc[h][0][r];
            poh[(quad * 4 + r) * 32 + 16 + l16] = (f16)oacc[h][1][r];
        }
    }
}

// ---------------------------------------------------------------------------
// Kernel 3: output projection with inline split-K combine + LDS Wp staging.
// grid (64 p-tiles, 2 o-halves, 4 b) = 512 blocks. Stages the block's 64 Wp
// rows fp32 -> f16 LDS. po gather is fully coalesced (quads complete the
// 64B att-row lines).
// ---------------------------------------------------------------------------
__global__ __launch_bounds__(256) void proj_mfma(
    const f16* __restrict__ po, const float* __restrict__ pl,
    const float* __restrict__ wp, const float* __restrict__ bp,
    float* __restrict__ out)
{
    __shared__ f16 wlds[64 * 136];     // 17.4 KB
    const int tid  = threadIdx.x;
    const int wave = tid >> 6;
    const int lane = tid & 63;
    const int quad = lane >> 4;
    const int l16  = lane & 15;
    const int pbase = blockIdx.x * 64;
    const int obase = blockIdx.y * 64;
    const int b     = blockIdx.z;
    const int p_col = pbase + wave * 16 + l16;

    // stage Wp rows obase..obase+63 fp32 -> f16
#pragma unroll
    for (int i = 0; i < 8; ++i) {
        const int idx = i * 256 + tid;
        const int o = idx >> 5, ch = idx & 31;
        float4 wv = *(const float4*)(wp + (size_t)(obase + o) * 128 + ch * 4);
        h16x2 a = __builtin_amdgcn_cvt_pkrtz(wv.x, wv.y);
        h16x2 c = __builtin_amdgcn_cvt_pkrtz(wv.z, wv.w);
        f16x4 h; h[0] = (f16)a[0]; h[1] = (f16)a[1]; h[2] = (f16)c[0]; h[3] = (f16)c[1];
        *(f16x4*)&wlds[o * 136 + ch * 4] = h;
    }
    __syncthreads();

    // combine split-K partials into att B-frags in registers
    f16x8 bf[4];
#pragma unroll
    for (int kc = 0; kc < 4; ++kc) {
        const int bh = b * 4 + kc;
        float sums[8] = {0.f, 0.f, 0.f, 0.f, 0.f, 0.f, 0.f, 0.f};
        float lt = 0.f;
#pragma unroll
        for (int s = 0; s < NSPLIT; ++s) {
            const size_t bq = (size_t)(s * 16 + bh) * NPIX + p_col;
            f16x8 a = *(const f16x8*)(po + bq * 32 + quad * 8);
#pragma unroll
            for (int j = 0; j < 8; ++j) sums[j] += (float)a[j];
            lt += pl[bq];
        }
        const float inv = 1.0f / lt;
#pragma unroll
        for (int j = 0; j < 4; ++j) {
            h16x2 pk = __builtin_amdgcn_cvt_pkrtz(sums[2 * j] * inv, sums[2 * j + 1] * inv);
            bf[kc][2 * j] = (f16)pk[0]; bf[kc][2 * j + 1] = (f16)pk[1];
        }
    }

    floatx4 acc[4];
#pragma unroll
    for (int m = 0; m < 4; ++m) acc[m] = floatx4{0.f, 0.f, 0.f, 0.f};
#pragma unroll
    for (int m = 0; m < 4; ++m)
#pragma unroll
        for (int kc = 0; kc < 4; ++kc) {
            f16x8 af = *(const f16x8*)&wlds[(m * 16 + l16) * 136 + kc * 32 + quad * 8];
            acc[m] = __builtin_amdgcn_mfma_f32_16x16x32_f16(af, bf[kc], acc[m], 0, 0, 0);
        }

#pragma unroll
    for (int m = 0; m < 4; ++m)
#pragma unroll
        for (int r = 0; r < 4; ++r) {
            const int o = obase + m * 16 + quad * 4 + r;
            out[((size_t)b * 128 + o) * NPIX + p_col] = acc[m][r] + bp[o];
        }
}

// ---------------------------------------------------------------------------
extern "C" void kernel_launch(void* const* d_in, const int* in_sizes, int n_in,
                              void* d_out, int out_size, void* d_ws, size_t ws_size,
                              hipStream_t stream)
{
    const float* x      = (const float*)d_in[0];
    const float* w_qkv  = (const float*)d_in[1];
    const float* w_proj = (const float*)d_in[2];
    const float* b_proj = (const float*)d_in[3];
    float* out = (float*)d_out;

    char* ws = (char*)d_ws;
    f16*   qh  = (f16*)(ws);                              // 4 MB [bh][p][32], pre-scaled
    f16*   kh  = (f16*)(ws + (4u << 20));                 // 4 MB [bh][p][32]
    f16*   vth = (f16*)(ws + (8u << 20));                 // 4 MB [bh][d][p]
    float* pl  = (float*)(ws + (12u << 20));              // 1 MB [4][16][4096] f32
    f16*   po  = (f16*)(ws + (13u << 20));                // 16.8 MB [4][16][4096][32] f16

    qkv_mfma<<<dim3(64, 6, 4), 256, 0, stream>>>(x, w_qkv, qh, kh, vth);
    attn_kernel<<<dim3(2048, 1, 1), 256, 0, stream>>>(qh, kh, vth, po, pl);
    proj_mfma<<<dim3(64, 2, 4), 256, 0, stream>>>(po, pl, w_proj, b_proj, out);
}